// Round 5
// baseline (85.807 us; speedup 1.0000x reference)
//
#include <hip/hip_runtime.h>
#include <math.h>

#define D_MODEL 1024
#define N_STATE 64
#define L_LEN   2048

// ---------------------------------------------------------------------------
// Kernel A: per-(d,n) parameter setup in double precision. One thread per
// (d,n) pair, 65536 threads total -- fully parallel, so the expensive f64
// transcendentals (atan2/log2/exp) cost ~1 us instead of serializing behind
// a per-block barrier. Writes 8 packed floats per (d,n) to workspace:
//   {th_hi, th_lo, ph, la_hi} {la_lo, lw, 2Re(Abar^16), |Abar^16|^2}
// th/la split hi(multiple of 2^-12)/lo so l*hi is exact fp32 for l < 2^11.
// ---------------------------------------------------------------------------
__global__ __launch_bounds__(256) void s4d_setup(
    const float* __restrict__ A_real, const float* __restrict__ A_imag,
    const float* __restrict__ B, const float* __restrict__ C,
    const float* __restrict__ log_dt, float* __restrict__ par)
{
    const int id = blockIdx.x * 256 + threadIdx.x;   // [0, 65536)
    const int d = id >> 6;
    const int n = id & 63;

    const double dt = exp((double)log_dt[d]);
    const double zr = 0.5 * dt * (double)A_real[n];
    const double zi = 0.5 * dt * (double)A_imag[n];
    const double dr = 1.0 - zr, di = -zi;
    const double inv = 1.0 / (dr*dr + di*di);
    const double nr = 1.0 + zr, ni = zi;
    const double sr = (nr*dr + ni*di) * inv;      // Abar
    const double si = (ni*dr - nr*di) * inv;
    const double dtB = dt * (double)B[n*D_MODEL + d];
    const double br = dtB * dr * inv;
    const double bi = dtB * zi * inv;
    const double cr = (double)C[(d*N_STATE + n)*2 + 0];
    const double ci = (double)C[(d*N_STATE + n)*2 + 1];
    const double wr = cr*br - ci*bi;              // w = Cc * Bbar
    const double wi = cr*bi + ci*br;

    const double INV2PI = 0.15915494309189535;
    const double threv = atan2(si, sr) * INV2PI;
    const double la    = 0.5 * log2(sr*sr + si*si);
    const double w2    = wr*wr + wi*wi;
    const double lw    = 0.5 * log2(fmax(w2, 1e-60));
    const double phrev = atan2(wi, wr) * INV2PI;

    const double th_hi = nearbyint(threv * 4096.0) * (1.0 / 4096.0);
    const double la_hi = nearbyint(la    * 4096.0) * (1.0 / 4096.0);

    // Abar^16 by 4 complex squarings in double:
    double pr = sr, pq = si;
    #pragma unroll
    for (int k = 0; k < 4; ++k) {
        double a2 = pr*pr - pq*pq;
        double b2 = 2.0*pr*pq;
        pr = a2; pq = b2;
    }

    float4 p0, p1;
    p0.x = (float)th_hi;
    p0.y = (float)(threv - th_hi);
    p0.z = (float)phrev;
    p0.w = (float)la_hi;
    p1.x = (float)(la - la_hi);
    p1.y = (float)lw;
    p1.z = (float)(2.0 * pr);            // 2*Re(Abar^16)
    p1.w = (float)(pr*pr + pq*pq);       // |Abar^16|^2
    float4* o = (float4*)(par + (size_t)id * 8);
    o[0] = p0;
    o[1] = p1;
}

// Closed-form single-term eval (validated: absmax 0.0039):
// |w| * |Abar|^l * cos(2*pi*(l*theta + phi))
__device__ __forceinline__ float eval_term(float lf,
                                           float th_hi, float th_lo, float ph0,
                                           float la_hi, float la_lo, float lw) {
    float amp = exp2f(fmaf(lf, la_hi, fmaf(lf, la_lo, lw)));
    float f1  = __builtin_amdgcn_fractf(lf * th_hi);           // exact product
    float ph  = __builtin_amdgcn_fractf(f1 + fmaf(lf, th_lo, ph0));
    return amp * __builtin_amdgcn_cosf(ph);                    // cos(2*pi*x)
}

// ---------------------------------------------------------------------------
// Kernel B: one block per d (4 waves; wave w owns l in [512w, 512w+512)).
// Lane split: q = lane>>4 (state quartet), g = lane&15 (l offset).
// Each lane runs 16 recurrence chains (states n = 4c+q) along l = lbase+g,
// stride 16:  y_{i+1} = 2Re(Abar^16) y_i - |Abar^16|^2 y_{i-1}.
// No LDS, no barriers, no f64: params come straight from ws (L2-broadcast).
// ---------------------------------------------------------------------------
__global__ __launch_bounds__(256) void s4d_main(
    const float* __restrict__ par, const float* __restrict__ Dv,
    float* __restrict__ out)
{
    const int d = blockIdx.x;
    const int t = threadIdx.x;
    const int wv   = t >> 6;
    const int lane = t & 63;
    const int q    = lane >> 4;
    const int g    = lane & 15;
    const int lbase = wv * 512 + g;

    const float4* pp = (const float4*)(par + (size_t)d * (N_STATE * 8));
    const float lf0 = (float)lbase;
    const float lf1 = (float)(lbase + 16);

    float y0[16], y1[16], ar[16], am[16];
    #pragma unroll
    for (int c = 0; c < 16; ++c) {
        const int n = (c << 2) | q;
        const float4 a = pp[2*n];
        const float4 b = pp[2*n + 1];
        ar[c] = b.z;
        am[c] = b.w;
        y0[c] = eval_term(lf0, a.x, a.y, a.z, a.w, b.x, b.y);
        y1[c] = eval_term(lf1, a.x, a.y, a.z, a.w, b.x, b.y);
    }

    const float dval = Dv[d];
    float* __restrict__ op = out + (size_t)d * L_LEN;

    #pragma unroll
    for (int i = 0; i < 32; ++i) {
        // tree-sum this lane's 16 chains (value at l = lbase + 16*i)
        float r8[8];
        #pragma unroll
        for (int k = 0; k < 8; ++k) r8[k] = y0[2*k] + y0[2*k+1];
        float r4a = r8[0] + r8[1], r4b = r8[2] + r8[3];
        float r4c = r8[4] + r8[5], r4d = r8[6] + r8[7];
        float sum = (r4a + r4b) + (r4c + r4d);
        // butterfly over the 4 state-quartets (lane bits 4,5)
        sum += __shfl_xor(sum, 16);
        sum += __shfl_xor(sum, 32);
        if (q == (i & 3)) {
            const int l = lbase + 16 * i;
            float v = sum;
            if (l == 0) v += dval;            // D * delta[0]
            op[l] = v;                        // 16 consecutive floats: 64B store
        }
        // advance all chains: y_{i+2} = ar*y_{i+1} - am*y_i
        #pragma unroll
        for (int c = 0; c < 16; ++c) {
            float yn = fmaf(ar[c], y1[c], -(am[c] * y0[c]));
            y0[c] = y1[c];
            y1[c] = yn;
        }
    }
}

extern "C" void kernel_launch(void* const* d_in, const int* in_sizes, int n_in,
                              void* d_out, int out_size, void* d_ws, size_t ws_size,
                              hipStream_t stream) {
    const float* A_real = (const float*)d_in[0];
    const float* A_imag = (const float*)d_in[1];
    const float* B      = (const float*)d_in[2];
    const float* C      = (const float*)d_in[3];
    const float* Dv     = (const float*)d_in[4];
    const float* log_dt = (const float*)d_in[5];
    float* out = (float*)d_out;
    float* par = (float*)d_ws;                 // 1024*64*8 floats = 2 MB
    (void)in_sizes; (void)n_in; (void)ws_size; (void)out_size;

    s4d_setup<<<dim3(D_MODEL * N_STATE / 256), dim3(256), 0, stream>>>(
        A_real, A_imag, B, C, log_dt, par);
    s4d_main<<<dim3(D_MODEL), dim3(256), 0, stream>>>(par, Dv, out);
}